// Round 1
// baseline (290.004 us; speedup 1.0000x reference)
//
#include <hip/hip_runtime.h>
#include <hip/hip_bf16.h>

typedef __attribute__((ext_vector_type(4))) float f32x4;
typedef __attribute__((ext_vector_type(8))) short s16x8;
typedef unsigned short ushort_t;

// ---------- helpers ----------
__device__ __forceinline__ ushort_t f2bf(float f) {
    union { float f; unsigned u; } v; v.f = f;
    unsigned r = v.u + 0x7fffu + ((v.u >> 16) & 1u);   // RNE
    return (ushort_t)(r >> 16);
}

__device__ __forceinline__ void gload16(const ushort_t* g, ushort_t* l) {
    __builtin_amdgcn_global_load_lds(
        (const __attribute__((address_space(1))) unsigned int*)g,
        (__attribute__((address_space(3))) unsigned int*)l,
        16, 0, 0);
}

// ---------- fp32 -> bf16 conversion (8 elems/thread) ----------
__global__ void cvt_bf16(const float* __restrict__ in, ushort_t* __restrict__ out, int n8) {
    int i = blockIdx.x * blockDim.x + threadIdx.x;
    if (i >= n8) return;
    const float4* p = (const float4*)in;
    float4 a = p[2 * i], b = p[2 * i + 1];
    s16x8 v;
    v[0] = (short)f2bf(a.x); v[1] = (short)f2bf(a.y);
    v[2] = (short)f2bf(a.z); v[3] = (short)f2bf(a.w);
    v[4] = (short)f2bf(b.x); v[5] = (short)f2bf(b.y);
    v[6] = (short)f2bf(b.z); v[7] = (short)f2bf(b.w);
    *(s16x8*)(out + (size_t)i * 8) = v;
}

// ---------- RoPE tables: [l][fi], l in [0,256), fi in [0,32) ----------
__global__ void rope_tab_k(float* __restrict__ cosT, float* __restrict__ sinT) {
    int i = blockIdx.x * blockDim.x + threadIdx.x;   // 8192 total
    int l = i >> 5, fi = i & 31;
    float inv = powf(10000.f, -2.f * (float)fi / 64.f);
    float ang = (float)l * inv;
    cosT[i] = cosf(ang);
    sinT[i] = sinf(ang);
}

// ---------- GEMM mainloop: C(128x128) = A(Mx1024) * W(Nx1024)^T ----------
// m97 structure: BK=32, 4 waves (2x2), 4x4 16x16x32 frags per wave,
// global_load_lds width 16, 2 barriers per K-step.
__device__ __forceinline__ void gemm_mainloop(const ushort_t* __restrict__ A,
                                              const ushort_t* __restrict__ W,
                                              ushort_t* As, ushort_t* Bs,
                                              f32x4 (&acc)[4][4]) {
    const int tid = threadIdx.x, lane = tid & 63, wid = tid >> 6;
    const int tm = blockIdx.x, tn = blockIdx.y;
    const int wm = wid >> 1, wn = wid & 1;
    const int c0 = wid * 128 + lane, c1 = c0 + 64;
    const size_t aoff0 = (size_t)(tm * 128 + (c0 >> 2)) * 1024 + (c0 & 3) * 8;
    const size_t aoff1 = (size_t)(tm * 128 + (c1 >> 2)) * 1024 + (c1 & 3) * 8;
    const size_t boff0 = (size_t)(tn * 128 + (c0 >> 2)) * 1024 + (c0 & 3) * 8;
    const size_t boff1 = (size_t)(tn * 128 + (c1 >> 2)) * 1024 + (c1 & 3) * 8;
    ushort_t* la0 = As + c0 * 8; ushort_t* la1 = As + c1 * 8;
    ushort_t* lb0 = Bs + c0 * 8; ushort_t* lb1 = Bs + c1 * 8;
    const int afr = (wm * 64 + (lane & 15)) * 32 + ((lane >> 4) << 3);
    const int bfr = (wn * 64 + (lane & 15)) * 32 + ((lane >> 4) << 3);

    for (int kk = 0; kk < 1024; kk += 32) {
        gload16(A + aoff0 + kk, la0);
        gload16(A + aoff1 + kk, la1);
        gload16(W + boff0 + kk, lb0);
        gload16(W + boff1 + kk, lb1);
        __syncthreads();
        s16x8 af[4], bfq[4];
#pragma unroll
        for (int i = 0; i < 4; ++i) {
            af[i] = *(const s16x8*)&As[afr + i * 512];
            bfq[i] = *(const s16x8*)&Bs[bfr + i * 512];
        }
#pragma unroll
        for (int mi = 0; mi < 4; ++mi)
#pragma unroll
            for (int ni = 0; ni < 4; ++ni)
                acc[mi][ni] = __builtin_amdgcn_mfma_f32_16x16x32_bf16(af[mi], bfq[ni], acc[mi][ni], 0, 0, 0);
        __syncthreads();
    }
}

// ---------- QKV projection + bias + RoPE -> bf16 ----------
__global__ __launch_bounds__(256) void gemm_qkv(const ushort_t* __restrict__ A,
                                                const ushort_t* __restrict__ Wqb,
                                                const ushort_t* __restrict__ Wkb,
                                                const ushort_t* __restrict__ Wvb,
                                                const float* __restrict__ bq,
                                                const float* __restrict__ bk,
                                                const float* __restrict__ bv,
                                                ushort_t* __restrict__ qb,
                                                ushort_t* __restrict__ kb,
                                                ushort_t* __restrict__ vb,
                                                const float* __restrict__ cosT,
                                                const float* __restrict__ sinT) {
    __shared__ ushort_t As[128 * 32];
    __shared__ ushort_t Bs[128 * 32];
    const int z = blockIdx.z;
    const ushort_t* W = (z == 0) ? Wqb : (z == 1) ? Wkb : Wvb;
    const float* bias = (z == 0) ? bq : (z == 1) ? bk : bv;
    ushort_t* outp = (z == 0) ? qb : (z == 1) ? kb : vb;
    const bool rope = (z < 2);

    f32x4 acc[4][4];
#pragma unroll
    for (int i = 0; i < 4; ++i)
#pragma unroll
        for (int j = 0; j < 4; ++j) acc[i][j] = (f32x4){0.f, 0.f, 0.f, 0.f};

    gemm_mainloop(A, W, As, Bs, acc);

    const int lane = threadIdx.x & 63, wid = threadIdx.x >> 6;
    const int wm = wid >> 1, wn = wid & 1;
#pragma unroll
    for (int mi = 0; mi < 4; ++mi) {
#pragma unroll
        for (int ni = 0; ni < 4; ++ni) {
            int col = blockIdx.y * 128 + wn * 64 + ni * 16 + (lane & 15);
            float bv_ = bias[col];
            int rb = blockIdx.x * 128 + wm * 64 + mi * 16 + ((lane >> 4) << 2);
#pragma unroll
            for (int r = 0; r < 4; ++r) {
                float v = acc[mi][ni][r] + bv_;
                float res;
                if (rope) {
                    int l = (rb + r) & 255;
                    int fi = (col & 63) >> 1;
                    float c = cosT[l * 32 + fi], s = sinT[l * 32 + fi];
                    float partner = __shfl_xor(v, 1);
                    res = (col & 1) ? (v * c + partner * s) : (v * c - partner * s);
                } else {
                    res = v;
                }
                outp[(size_t)(rb + r) * 1024 + col] = f2bf(res);
            }
        }
    }
}

// ---------- output projection + bias -> fp32 ----------
__global__ __launch_bounds__(256) void gemm_out(const ushort_t* __restrict__ A,
                                                const ushort_t* __restrict__ W,
                                                const float* __restrict__ bias,
                                                float* __restrict__ outp) {
    __shared__ ushort_t As[128 * 32];
    __shared__ ushort_t Bs[128 * 32];
    f32x4 acc[4][4];
#pragma unroll
    for (int i = 0; i < 4; ++i)
#pragma unroll
        for (int j = 0; j < 4; ++j) acc[i][j] = (f32x4){0.f, 0.f, 0.f, 0.f};

    gemm_mainloop(A, W, As, Bs, acc);

    const int lane = threadIdx.x & 63, wid = threadIdx.x >> 6;
    const int wm = wid >> 1, wn = wid & 1;
#pragma unroll
    for (int mi = 0; mi < 4; ++mi) {
#pragma unroll
        for (int ni = 0; ni < 4; ++ni) {
            int col = blockIdx.y * 128 + wn * 64 + ni * 16 + (lane & 15);
            float bv_ = bias[col];
            int rb = blockIdx.x * 128 + wm * 64 + mi * 16 + ((lane >> 4) << 2);
#pragma unroll
            for (int r = 0; r < 4; ++r)
                outp[(size_t)(rb + r) * 1024 + col] = acc[mi][ni][r] + bv_;
        }
    }
}

// ---------- fused causal attention per (b,h): softmax(QK^T/sqrt(64))V ----------
// 8 waves x 32 q-rows; K in LDS [256][72] (padded), V transposed [64][264],
// P redistributed via padded per-wave LDS slice.
__global__ __launch_bounds__(512) void attn_kernel(const ushort_t* __restrict__ qb,
                                                   const ushort_t* __restrict__ kb,
                                                   const ushort_t* __restrict__ vb,
                                                   ushort_t* __restrict__ ab) {
    __shared__ ushort_t Ks[256 * 72];
    __shared__ ushort_t Vt[64 * 264];
    __shared__ ushort_t Ps[8][16 * 264];
    const int bh = blockIdx.x, b = bh >> 4, h = bh & 15;
    const int tid = threadIdx.x, lane = tid & 63, wid = tid >> 6;
    const size_t base = (size_t)b * 256 * 1024 + (size_t)h * 64;

    // stage K (row-major, padded rows of 72)
#pragma unroll
    for (int it = 0; it < 4; ++it) {
        int c = tid + it * 512;
        int row = c >> 3, seg = c & 7;
        *(s16x8*)&Ks[row * 72 + seg * 8] =
            *(const s16x8*)&kb[base + (size_t)row * 1024 + seg * 8];
    }
    // stage V transposed: Vt[d][k]
#pragma unroll
    for (int it = 0; it < 4; ++it) {
        int c = tid + it * 512;
        int k = c >> 3, seg = c & 7;
        s16x8 v8 = *(const s16x8*)&vb[base + (size_t)k * 1024 + seg * 8];
#pragma unroll
        for (int j = 0; j < 8; ++j)
            Vt[(seg * 8 + j) * 264 + k] = (ushort_t)v8[j];
    }
    __syncthreads();

#pragma unroll
    for (int ch = 0; ch < 2; ++ch) {
        const int q0 = wid * 32 + ch * 16;
        s16x8 aq0 = *(const s16x8*)&qb[base + (size_t)(q0 + (lane & 15)) * 1024 + ((lane >> 4) << 3)];
        s16x8 aq1 = *(const s16x8*)&qb[base + (size_t)(q0 + (lane & 15)) * 1024 + 32 + ((lane >> 4) << 3)];

        f32x4 sacc[16];
#pragma unroll
        for (int n = 0; n < 16; ++n) sacc[n] = (f32x4){0.f, 0.f, 0.f, 0.f};
#pragma unroll
        for (int n = 0; n < 16; ++n) {
            const int kr = (n * 16 + (lane & 15)) * 72 + ((lane >> 4) << 3);
            s16x8 b0 = *(const s16x8*)&Ks[kr];
            s16x8 b1 = *(const s16x8*)&Ks[kr + 32];
            sacc[n] = __builtin_amdgcn_mfma_f32_16x16x32_bf16(aq0, b0, sacc[n], 0, 0, 0);
            sacc[n] = __builtin_amdgcn_mfma_f32_16x16x32_bf16(aq1, b1, sacc[n], 0, 0, 0);
        }

        float rinv[4];
#pragma unroll
        for (int r = 0; r < 4; ++r) {
            const int row = q0 + ((lane >> 4) << 2) + r;
            float m = -1e30f;
#pragma unroll
            for (int n = 0; n < 16; ++n) {
                int col = n * 16 + (lane & 15);
                float v = (col <= row) ? sacc[n][r] * 0.125f : -1e30f;
                sacc[n][r] = v;
                m = fmaxf(m, v);
            }
            m = fmaxf(m, __shfl_xor(m, 1));
            m = fmaxf(m, __shfl_xor(m, 2));
            m = fmaxf(m, __shfl_xor(m, 4));
            m = fmaxf(m, __shfl_xor(m, 8));
            float sum = 0.f;
#pragma unroll
            for (int n = 0; n < 16; ++n) {
                float p = __expf(sacc[n][r] - m);
                sacc[n][r] = p;
                sum += p;
            }
            sum += __shfl_xor(sum, 1);
            sum += __shfl_xor(sum, 2);
            sum += __shfl_xor(sum, 4);
            sum += __shfl_xor(sum, 8);
            rinv[r] = 1.f / sum;
#pragma unroll
            for (int n = 0; n < 16; ++n)
                Ps[wid][(((lane >> 4) << 2) + r) * 264 + n * 16 + (lane & 15)] = f2bf(sacc[n][r]);
        }
        __syncthreads();

        f32x4 oa[4];
#pragma unroll
        for (int dt = 0; dt < 4; ++dt) oa[dt] = (f32x4){0.f, 0.f, 0.f, 0.f};
#pragma unroll
        for (int ks = 0; ks < 8; ++ks) {
            s16x8 pf = *(const s16x8*)&Ps[wid][(lane & 15) * 264 + ks * 32 + ((lane >> 4) << 3)];
#pragma unroll
            for (int dt = 0; dt < 4; ++dt) {
                s16x8 vf = *(const s16x8*)&Vt[(dt * 16 + (lane & 15)) * 264 + ks * 32 + ((lane >> 4) << 3)];
                oa[dt] = __builtin_amdgcn_mfma_f32_16x16x32_bf16(pf, vf, oa[dt], 0, 0, 0);
            }
        }
#pragma unroll
        for (int dt = 0; dt < 4; ++dt) {
#pragma unroll
            for (int r = 0; r < 4; ++r) {
                int row = q0 + ((lane >> 4) << 2) + r;
                int col = h * 64 + dt * 16 + (lane & 15);
                ab[(size_t)(b * 256 + row) * 1024 + col] = f2bf(oa[dt][r] * rinv[r]);
            }
        }
        __syncthreads();
    }
}

// ---------- launch ----------
extern "C" void kernel_launch(void* const* d_in, const int* in_sizes, int n_in,
                              void* d_out, int out_size, void* d_ws, size_t ws_size,
                              hipStream_t stream) {
    (void)in_sizes; (void)n_in; (void)out_size;
    const float* x  = (const float*)d_in[0];
    const float* Wq = (const float*)d_in[1];
    const float* bq = (const float*)d_in[2];
    const float* Wk = (const float*)d_in[3];
    const float* bk = (const float*)d_in[4];
    const float* Wv = (const float*)d_in[5];
    const float* bv = (const float*)d_in[6];
    const float* Wo = (const float*)d_in[7];
    const float* bo = (const float*)d_in[8];
    float* out = (float*)d_out;

    const size_t M = 16384, E = 1024;
    char* ws = (char*)d_ws;
    ushort_t* xb  = (ushort_t*)ws;               // M*E  (reused as attn-out later)
    ushort_t* wqb = xb + M * E;
    ushort_t* wkb = wqb + E * E;
    ushort_t* wvb = wkb + E * E;
    ushort_t* wob = wvb + E * E;
    ushort_t* qb  = wob + E * E;
    ushort_t* kb  = qb + M * E;
    ushort_t* vb  = kb + M * E;
    float* cosT   = (float*)(vb + M * E);
    float* sinT   = cosT + 256 * 32;
    ushort_t* ab  = xb;                          // alias: x no longer needed post-QKV

    size_t need = (M * E * 4 + E * E * 4) * 2 + 2 * 256 * 32 * 4;
    if (ws_size < need) return;   // cannot proceed safely

    cvt_bf16<<<8192, 256, 0, stream>>>(x, xb, (int)(M * E / 8));
    cvt_bf16<<<512, 256, 0, stream>>>(Wq, wqb, (int)(E * E / 8));
    cvt_bf16<<<512, 256, 0, stream>>>(Wk, wkb, (int)(E * E / 8));
    cvt_bf16<<<512, 256, 0, stream>>>(Wv, wvb, (int)(E * E / 8));
    cvt_bf16<<<512, 256, 0, stream>>>(Wo, wob, (int)(E * E / 8));
    rope_tab_k<<<32, 256, 0, stream>>>(cosT, sinT);

    gemm_qkv<<<dim3(128, 8, 3), 256, 0, stream>>>(xb, wqb, wkb, wvb, bq, bk, bv,
                                                  qb, kb, vb, cosT, sinT);
    attn_kernel<<<1024, 512, 0, stream>>>(qb, kb, vb, ab);
    gemm_out<<<dim3(128, 8, 1), 256, 0, stream>>>(ab, wob, bo, out);
}